// Round 1
// baseline (1201.001 us; speedup 1.0000x reference)
//
#include <hip/hip_runtime.h>
#include <hip/hip_bf16.h>

// Problem constants (fixed by the reference):
//   B=2, X=96, Y=96, Z=64, C=32, K=16 (8 bg + 8 fg), LOG_PROB_SCALE=200
#define NVOX (2 * 96 * 96 * 64)
#define C_DIM 32
#define K_TOT 16

// d_ws layout (bytes):
//   [0,      65536)  Linv[16][32][32] fp32 (lower triangular, upper garbage-safe: written 0)
//   [65536,  67584)  u[16][32] = Linv_k * mu_k
//   [67584,  67648)  h[16]     = (const - logdet_k) / 200
//   [67648,  67712)  w[16]
#define WS_LINV 0
#define WS_U    65536
#define WS_H    67584
#define WS_W    67648

__global__ void gmm_prep_kernel(const float* __restrict__ wb, const float* __restrict__ mb,
                                const float* __restrict__ Lb, const float* __restrict__ wf,
                                const float* __restrict__ mf, const float* __restrict__ Lf,
                                float* __restrict__ ws) {
    int k = threadIdx.x;
    if (k >= K_TOT) return;
    const float* L  = (k < 8) ? (Lb + k * 1024) : (Lf + (k - 8) * 1024);
    const float* mu = (k < 8) ? (mb + k * 32)   : (mf + (k - 8) * 32);
    float wk        = (k < 8) ? wb[k]           : wf[k - 8];

    float* Li = ws + (WS_LINV / 4) + k * 1024;
    float* u  = ws + (WS_U / 4) + k * 32;
    float* h  = ws + (WS_H / 4);
    float* w  = ws + (WS_W / 4);

    // Forward substitution: solve L * Li = I (Li is lower triangular).
    for (int j = 0; j < 32; ++j) {
        for (int i = 0; i < 32; ++i) {
            if (i < j) { Li[i * 32 + j] = 0.0f; continue; }
            float s = (i == j) ? 1.0f : 0.0f;
            for (int m = j; m < i; ++m) s -= L[i * 32 + m] * Li[m * 32 + j];
            Li[i * 32 + j] = s / L[i * 32 + i];
        }
    }
    float ld = 0.0f;
    for (int i = 0; i < 32; ++i) ld += logf(L[i * 32 + i]);
    for (int d = 0; d < 32; ++d) {
        float s = 0.0f;
        for (int c = 0; c <= d; ++c) s += Li[d * 32 + c] * mu[c];
        u[d] = s;
    }
    const float cconst = -0.5f * 32.0f * 1.8378770664093453f;  // -C/2 * log(2*pi)
    h[k] = (cconst - ld) * (1.0f / 200.0f);
    w[k] = wk;
}

__global__ __launch_bounds__(256) void gmm_density_kernel(
        const float* __restrict__ fm, const float* __restrict__ ws,
        float* __restrict__ out) {
    int v = blockIdx.x * 256 + threadIdx.x;
    // v < NVOX guaranteed by exact grid (NVOX % 256 == 0)

    const float* __restrict__ Linv = ws + (WS_LINV / 4);
    const float* __restrict__ u    = ws + (WS_U / 4);
    const float* __restrict__ h    = ws + (WS_H / 4);
    const float* __restrict__ w    = ws + (WS_W / 4);

    // Load x[32] for this voxel (contiguous 128 B per voxel).
    float x[C_DIM];
    const float4* xp = (const float4*)(fm + (size_t)v * C_DIM);
#pragma unroll
    for (int i = 0; i < 8; ++i) {
        float4 t = xp[i];
        x[4 * i + 0] = t.x; x[4 * i + 1] = t.y;
        x[4 * i + 2] = t.z; x[4 * i + 3] = t.w;
    }

    float dens = 0.0f;
    for (int k = 0; k < K_TOT; ++k) {
        const float* __restrict__ Lk = Linv + k * 1024;
        const float* __restrict__ uk = u + k * 32;
        float q = 0.0f;
#pragma unroll
        for (int d = 0; d < 32; ++d) {
            float yd = -uk[d];
#pragma unroll
            for (int c = 0; c <= d; ++c) yd = fmaf(Lk[d * 32 + c], x[c], yd);
            q = fmaf(yd, yd, q);
        }
        // t = (const - logdet)/200 - q/400 ; dens += w_k * exp(t)
        dens += w[k] * __expf(fmaf(q, -2.5e-3f, h[k]));
    }

    // z = v % 64 (Z == 64); the torch loop leaves z == Z-1 at zero.
    if ((v & 63) == 63) dens = 0.0f;
    out[v] = dens;
}

extern "C" void kernel_launch(void* const* d_in, const int* in_sizes, int n_in,
                              void* d_out, int out_size, void* d_ws, size_t ws_size,
                              hipStream_t stream) {
    const float* fm = (const float*)d_in[0];
    const float* wb = (const float*)d_in[1];
    const float* mb = (const float*)d_in[2];
    const float* Lb = (const float*)d_in[3];
    const float* wf = (const float*)d_in[4];
    const float* mf = (const float*)d_in[5];
    const float* Lf = (const float*)d_in[6];
    float* out = (float*)d_out;
    float* ws  = (float*)d_ws;

    gmm_prep_kernel<<<1, 64, 0, stream>>>(wb, mb, Lb, wf, mf, Lf, ws);
    gmm_density_kernel<<<NVOX / 256, 256, 0, stream>>>(fm, ws, out);
}

// Round 2
// 484.802 us; speedup vs baseline: 2.4773x; 2.4773x over previous
//
#include <hip/hip_runtime.h>
#include <hip/hip_bf16.h>

// Problem constants (fixed by the reference):
//   B=2, X=96, Y=96, Z=64, C=32, K=16 (8 bg + 8 fg), LOG_PROB_SCALE=200
#define NVOX (2 * 96 * 96 * 64)
#define C_DIM 32
#define K_TOT 16

// d_ws layout (floats):
//   per component k (stride 576, 16-dword aligned):
//     [k*576 + 0,   k*576 + 528)  packed lower-tri Linv_k: idx = d*(d+1)/2 + c
//     [k*576 + 528, k*576 + 560)  u_k = Linv_k * mu_k
//   [9216, 9232)  h[16] = (const - logdet_k) / 200
//   [9232, 9248)  w[16]
#define WS_STRIDE 576
#define WS_U_OFF  528
#define WS_H      9216
#define WS_W      9232

__global__ void gmm_prep_kernel(const float* __restrict__ wb, const float* __restrict__ mb,
                                const float* __restrict__ Lb, const float* __restrict__ wf,
                                const float* __restrict__ mf, const float* __restrict__ Lf,
                                float* __restrict__ ws) {
    int k   = blockIdx.x;   // 16 blocks, one per component
    int tid = threadIdx.x;  // 64 threads

    __shared__ float Lsh[1024];   // L_k row-major
    __shared__ float Lish[1024];  // Linv_k row-major

    const float* L  = (k < 8) ? (Lb + k * 1024) : (Lf + (k - 8) * 1024);
    const float* mu = (k < 8) ? (mb + k * 32)   : (mf + (k - 8) * 32);

    for (int i = tid; i < 1024; i += 64) Lsh[i] = L[i];
    __syncthreads();

    float* Wk = ws + k * WS_STRIDE;

    if (tid < 32) {
        int j = tid;  // this thread solves column j of Linv: L * col = e_j
        float col[32];
#pragma unroll
        for (int i = 0; i < 32; ++i) col[i] = 0.0f;
#pragma unroll
        for (int i = 0; i < 32; ++i) {
            float s = (i == j) ? 1.0f : 0.0f;
#pragma unroll
            for (int m = 0; m < i; ++m) s = fmaf(-Lsh[i * 32 + m], col[m], s);
            float val = s / Lsh[i * 32 + i];
            col[i] = (i >= j) ? val : 0.0f;  // for i<j s==0 anyway, but be explicit
        }
#pragma unroll
        for (int i = 0; i < 32; ++i) Lish[i * 32 + j] = col[i];
        // packed triangular write: entry (d, j) for d >= j
#pragma unroll
        for (int d = 0; d < 32; ++d)
            if (d >= j) Wk[d * (d + 1) / 2 + j] = col[d];
    }
    __syncthreads();

    if (tid < 32) {
        int d = tid;  // u[d] = sum_{c<=d} Linv[d][c] * mu[c]
        float s = 0.0f;
        for (int c = 0; c <= d; ++c) s = fmaf(Lish[d * 32 + c], mu[c], s);
        Wk[WS_U_OFF + d] = s;
    }
    if (tid == 0) {
        float ld = 0.0f;
        for (int i = 0; i < 32; ++i) ld += logf(Lsh[i * 32 + i]);
        const float cconst = -0.5f * 32.0f * 1.8378770664093453f;  // -C/2*log(2pi)
        ws[WS_H + k] = (cconst - ld) * (1.0f / 200.0f);
        ws[WS_W + k] = (k < 8) ? wb[k] : wf[k - 8];
    }
}

__global__ __launch_bounds__(256) void gmm_density_kernel(
        const float* __restrict__ fm, const float* __restrict__ ws,
        float* __restrict__ out) {
    int t = blockIdx.x * 256 + threadIdx.x;   // one thread = 2 voxels
    size_t v0 = (size_t)t * 2;

    // Load x for voxels v0, v0+1 (256 B contiguous per thread).
    float x0[C_DIM], x1[C_DIM];
    const float4* xp = (const float4*)(fm + v0 * C_DIM);
#pragma unroll
    for (int i = 0; i < 8; ++i) {
        float4 a = xp[i];
        x0[4 * i + 0] = a.x; x0[4 * i + 1] = a.y;
        x0[4 * i + 2] = a.z; x0[4 * i + 3] = a.w;
        float4 b = xp[i + 8];
        x1[4 * i + 0] = b.x; x1[4 * i + 1] = b.y;
        x1[4 * i + 2] = b.z; x1[4 * i + 3] = b.w;
    }

    const float* __restrict__ h = ws + WS_H;
    const float* __restrict__ w = ws + WS_W;

    float d0 = 0.0f, d1 = 0.0f;
    for (int k = 0; k < K_TOT; ++k) {
        const float* __restrict__ Lk = ws + k * WS_STRIDE;  // packed tri + u
        float q0 = 0.0f, q1 = 0.0f;
#pragma unroll
        for (int d = 0; d < 32; ++d) {
            float ud = Lk[WS_U_OFF + d];
            float y0 = -ud, y1 = -ud;
#pragma unroll
            for (int c = 0; c <= d; ++c) {
                float l = Lk[d * (d + 1) / 2 + c];   // compile-time packed index
                y0 = fmaf(l, x0[c], y0);
                y1 = fmaf(l, x1[c], y1);
            }
            q0 = fmaf(y0, y0, q0);
            q1 = fmaf(y1, y1, q1);
        }
        float hk = h[k], wk = w[k];
        d0 += wk * __expf(fmaf(q0, -2.5e-3f, hk));
        d1 += wk * __expf(fmaf(q1, -2.5e-3f, hk));
    }

    // Z == 64: zero the z == 63 slice. v0 is even so only v0+1 can hit it.
    if (((v0 + 1) & 63) == 63) d1 = 0.0f;
    ((float2*)out)[t] = make_float2(d0, d1);
}

extern "C" void kernel_launch(void* const* d_in, const int* in_sizes, int n_in,
                              void* d_out, int out_size, void* d_ws, size_t ws_size,
                              hipStream_t stream) {
    const float* fm = (const float*)d_in[0];
    const float* wb = (const float*)d_in[1];
    const float* mb = (const float*)d_in[2];
    const float* Lb = (const float*)d_in[3];
    const float* wf = (const float*)d_in[4];
    const float* mf = (const float*)d_in[5];
    const float* Lf = (const float*)d_in[6];
    float* out = (float*)d_out;
    float* ws  = (float*)d_ws;

    gmm_prep_kernel<<<K_TOT, 64, 0, stream>>>(wb, mb, Lb, wf, mf, Lf, ws);
    gmm_density_kernel<<<NVOX / 512, 256, 0, stream>>>(fm, ws, out);
}

// Round 3
// 247.206 us; speedup vs baseline: 4.8583x; 1.9611x over previous
//
#include <hip/hip_runtime.h>
#include <hip/hip_bf16.h>
#include <cstring>

// Problem constants: B=2, X=96, Y=96, Z=64, C=32, K=16, LOG_PROB_SCALE=200
#define NVOX (2 * 96 * 96 * 64)
#define K_TOT 16
#define N_TILES (NVOX / 128)   // 9216 tiles of 128 voxels

typedef __attribute__((ext_vector_type(8)))  short short8;   // 8 bf16 (A/B frag)
typedef __attribute__((ext_vector_type(16))) float f32x16;   // C/D frag

// ws layout:
//   bytes [0, 32768): A-frags bf16, ushort idx ((kc*2 + half)*64 + lane)*8 + j
//       = Linv[kc][m = lane&31][c = half*16 + (lane>>5)*8 + j]
//   floats [8192, 8704): uf[kc*32 + (lane>>5)*16 + reg] = -u_kc[(reg&3)+8*(reg>>2)+4*(lane>>5)]
//   floats [8704, 8736): pairs (h2[kc], w[kc]); h2 = log2e*(const - logdet)/200
#define WS_UF 8192
#define WS_HW 8704
#define WS_FLOATS 8736   // 34944 bytes = 2184 float4

static __device__ __forceinline__ unsigned short f2b(float f) {
    __hip_bfloat16 h = __float2bfloat16(f);
    unsigned short u;
    __builtin_memcpy(&u, &h, 2);
    return u;
}

__global__ void gmm_prep_kernel(const float* __restrict__ wb, const float* __restrict__ mb,
                                const float* __restrict__ Lb, const float* __restrict__ wf,
                                const float* __restrict__ mf, const float* __restrict__ Lf,
                                float* __restrict__ ws) {
    int k   = blockIdx.x;   // component
    int tid = threadIdx.x;  // 64 threads

    __shared__ float Lsh[1024];   // L_k row-major
    __shared__ float Lish[1024];  // Linv_k row-major (upper tri = 0)
    __shared__ float ush[32];     // u = Linv * mu

    const float* L  = (k < 8) ? (Lb + k * 1024) : (Lf + (k - 8) * 1024);
    const float* mu = (k < 8) ? (mb + k * 32)   : (mf + (k - 8) * 32);

    for (int i = tid; i < 1024; i += 64) Lsh[i] = L[i];
    __syncthreads();

    if (tid < 32) {
        int j = tid;  // solve column j: L * col = e_j
        float col[32];
#pragma unroll
        for (int i = 0; i < 32; ++i) {
            float s = (i == j) ? 1.0f : 0.0f;
#pragma unroll
            for (int m = 0; m < i; ++m) s = fmaf(-Lsh[i * 32 + m], col[m], s);
            float val = s / Lsh[i * 32 + i];
            col[i] = (i >= j) ? val : 0.0f;
        }
#pragma unroll
        for (int i = 0; i < 32; ++i) Lish[i * 32 + j] = col[i];
    }
    __syncthreads();
    if (tid < 32) {
        int d = tid;
        float s = 0.0f;
        for (int c = 0; c <= d; ++c) s = fmaf(Lish[d * 32 + c], mu[c], s);
        ush[d] = s;
    }
    __syncthreads();

    // A-fragments in MFMA 32x32x16 operand order, bf16.
    unsigned short* wsA = (unsigned short*)ws;
    int m  = tid & 31;   // outdim row
    int kq = tid >> 5;   // k-half-of-8 within the MFMA's K=16
#pragma unroll
    for (int hf = 0; hf < 2; ++hf) {  // channel halves 0..15 / 16..31
        unsigned short* dst = wsA + (size_t)(((k * 2 + hf) * 64 + tid) * 8);
#pragma unroll
        for (int j = 0; j < 8; ++j)
            dst[j] = f2b(Lish[m * 32 + hf * 16 + kq * 8 + j]);
    }
    // -u in C/D fragment order
    if (tid < 32) {
        int h = tid >> 4, r = tid & 15;
        ws[WS_UF + k * 32 + tid] = -ush[(r & 3) + 8 * (r >> 2) + 4 * h];
    }
    if (tid == 0) {
        float ld = 0.0f;
        for (int i = 0; i < 32; ++i) ld += logf(Lsh[i * 32 + i]);
        const float cconst = -0.5f * 32.0f * 1.8378770664093453f;  // -C/2*log(2pi)
        const float log2e  = 1.4426950408889634f;
        ws[WS_HW + k * 2]     = (cconst - ld) * (1.0f / 200.0f) * log2e;
        ws[WS_HW + k * 2 + 1] = (k < 8) ? wb[k] : wf[k - 8];
    }
}

__global__ __launch_bounds__(256) void gmm_density_kernel(
        const float* __restrict__ fm, const float* __restrict__ ws,
        float* __restrict__ out) {
    __shared__ __align__(16) float smem[WS_FLOATS];
    {
        const float4* src = (const float4*)ws;
        float4* dst = (float4*)smem;
        for (int i = threadIdx.x; i < WS_FLOATS / 4; i += 256) dst[i] = src[i];
    }
    __syncthreads();
    const unsigned short* sWf = (const unsigned short*)smem;
    const float* sUf = smem + WS_UF;
    const float* sHW = smem + WS_HW;

    const int lane = threadIdx.x & 63;
    const int c    = lane & 31;   // voxel within 32-group / outdim col
    const int h    = lane >> 5;   // half-wave
    const int nwaves = (gridDim.x * 256) >> 6;
    const int gwave  = (blockIdx.x * 256 + (int)threadIdx.x) >> 6;

    const float SCALE = -0.0036067376022224085f;  // -log2(e)/400

    for (int tile = gwave; tile < N_TILES; tile += nwaves) {
        size_t vbase = (size_t)tile * 128;

        // Load + convert B-fragments: 4 groups of 32 voxels, channel halves per h.
        short8 Blo[4], Bhi[4];
#pragma unroll
        for (int g = 0; g < 4; ++g) {
            const float* xb = fm + (vbase + g * 32 + c) * 32 + h * 8;
            float4 a0 = *(const float4*)(xb + 0);
            float4 a1 = *(const float4*)(xb + 4);
            float4 b0 = *(const float4*)(xb + 16);
            float4 b1 = *(const float4*)(xb + 20);
            short8 lo, hi;
            lo[0] = (short)f2b(a0.x); lo[1] = (short)f2b(a0.y);
            lo[2] = (short)f2b(a0.z); lo[3] = (short)f2b(a0.w);
            lo[4] = (short)f2b(a1.x); lo[5] = (short)f2b(a1.y);
            lo[6] = (short)f2b(a1.z); lo[7] = (short)f2b(a1.w);
            hi[0] = (short)f2b(b0.x); hi[1] = (short)f2b(b0.y);
            hi[2] = (short)f2b(b0.z); hi[3] = (short)f2b(b0.w);
            hi[4] = (short)f2b(b1.x); hi[5] = (short)f2b(b1.y);
            hi[6] = (short)f2b(b1.z); hi[7] = (short)f2b(b1.w);
            Blo[g] = lo; Bhi[g] = hi;
        }

        float dens[4] = {0.f, 0.f, 0.f, 0.f};
        for (int kc = 0; kc < K_TOT; ++kc) {
            short8 Alo = *(const short8*)(sWf + ((size_t)(kc * 2 + 0) * 64 + lane) * 8);
            short8 Ahi = *(const short8*)(sWf + ((size_t)(kc * 2 + 1) * 64 + lane) * 8);
            f32x16 Cu;
            {
                const float4* up = (const float4*)(sUf + kc * 32 + h * 16);
                float4 u0 = up[0], u1 = up[1], u2 = up[2], u3 = up[3];
                Cu[0]  = u0.x; Cu[1]  = u0.y; Cu[2]  = u0.z; Cu[3]  = u0.w;
                Cu[4]  = u1.x; Cu[5]  = u1.y; Cu[6]  = u1.z; Cu[7]  = u1.w;
                Cu[8]  = u2.x; Cu[9]  = u2.y; Cu[10] = u2.z; Cu[11] = u2.w;
                Cu[12] = u3.x; Cu[13] = u3.y; Cu[14] = u3.z; Cu[15] = u3.w;
            }
            float h2 = sHW[kc * 2], wk = sHW[kc * 2 + 1];
#pragma unroll
            for (int g = 0; g < 4; ++g) {
                f32x16 d = __builtin_amdgcn_mfma_f32_32x32x16_bf16(Alo, Blo[g], Cu, 0, 0, 0);
                d = __builtin_amdgcn_mfma_f32_32x32x16_bf16(Ahi, Bhi[g], d, 0, 0, 0);
                float p = 0.f;
#pragma unroll
                for (int r = 0; r < 16; ++r) p = fmaf(d[r], d[r], p);
                p += __shfl_xor(p, 32);
                dens[g] = fmaf(wk, exp2f(fmaf(p, SCALE, h2)), dens[g]);
            }
        }

        // Store: half-wave h writes groups {2h, 2h+1}; zero the z==63 slice
        // (z = (g*32 + c) & 63 == 63  <=>  c==31 && g odd).
#pragma unroll
        for (int gg = 0; gg < 2; ++gg) {
            int g = h * 2 + gg;
            float val = dens[g];
            if (c == 31 && (g & 1)) val = 0.f;
            out[vbase + g * 32 + c] = val;
        }
    }
}

extern "C" void kernel_launch(void* const* d_in, const int* in_sizes, int n_in,
                              void* d_out, int out_size, void* d_ws, size_t ws_size,
                              hipStream_t stream) {
    const float* fm = (const float*)d_in[0];
    const float* wb = (const float*)d_in[1];
    const float* mb = (const float*)d_in[2];
    const float* Lb = (const float*)d_in[3];
    const float* wf = (const float*)d_in[4];
    const float* mf = (const float*)d_in[5];
    const float* Lf = (const float*)d_in[6];
    float* out = (float*)d_out;
    float* ws  = (float*)d_ws;

    gmm_prep_kernel<<<K_TOT, 64, 0, stream>>>(wb, mb, Lb, wf, mf, Lf, ws);
    gmm_density_kernel<<<768, 256, 0, stream>>>(fm, ws, out);
}